// Round 4
// baseline (445.784 us; speedup 1.0000x reference)
//
#include <hip/hip_runtime.h>

// Problem constants (from reference)
#define B_      128
#define NPIX    32      // N = M = 32
#define NNEO    30      // N-2
#define CSTATE  19      // state channels
#define OUTD    21      // OUT_DIM
#define ITERS   10
#define THRESHV 0.0007f

#define STATE_ELEMS (B_ * NPIX * NPIX * CSTATE)   // 2,490,368 floats per buffer
#define NCELLS      (B_ * NNEO * NNEO)            // 115,200
#define CLASS_ELEMS (NCELLS * 3)                  // 345,600
#define HSTRIDE 31    // s_h cell stride: gcd(31,32)=1 -> conflict-free

// ---------------------------------------------------------------------------
// init: zero ONLY the borders of both state buffers (interiors are fully
// written by step t=0 / t=1 before being read). 124 border cells * 19 ch.
// perc needs no init: the FIRST step derives (px,py)=(i,j) itself.
// ---------------------------------------------------------------------------
__global__ void nca_init(float* __restrict__ stateA, float* __restrict__ stateB) {
    int idx = blockIdx.x * blockDim.x + threadIdx.x;
    const int total = B_ * 124 * CSTATE;
    if (idx >= total) return;
    int c  = idx % CSTATE;
    int t2 = idx / CSTATE;
    int cell = t2 % 124;
    int b    = t2 / 124;
    int i, j;
    if (cell < 32)      { i = 0;  j = cell; }
    else if (cell < 64) { i = 31; j = cell - 32; }
    else { int k = cell - 64; i = 1 + (k >> 1); j = (k & 1) ? 31 : 0; }
    size_t off = (((size_t)b * NPIX + i) * NPIX + j) * CSTATE + c;
    stateA[off] = 0.0f;
    stateB[off] = 0.0f;
}

// ---------------------------------------------------------------------------
// One NCA step. Block = (batch b, row-group rg): row groups {8,8,7,7}, 30
// cols. 512 threads: waves 0-3 compute outputs [0,15), waves 4-7 outputs
// [15,30) of the same cells (2 threads per cell, split on output dim).
// All weight loops fully unrolled -> static s_load offsets -> compiler can
// batch scalar loads ahead of the FMA groups instead of lgkmcnt(0) stalls.
// ---------------------------------------------------------------------------
template<bool FIRST, bool LAST>
__global__ __launch_bounds__(512, 4)
void nca_step(const float* __restrict__ img,
              const float* __restrict__ W1, const float* __restrict__ b1,
              const float* __restrict__ W2, const float* __restrict__ b2,
              const float* __restrict__ W3, const float* __restrict__ b3,
              const float* __restrict__ state_old, float* __restrict__ state_new,
              int* perc, float* __restrict__ guesses_out,
              float* __restrict__ class_out) {
    __shared__ float s_state[10 * NPIX * CSTATE];   // 6080 floats = 24.3 KB
    __shared__ float s_img[NPIX * NPIX];            // 1024 floats = 4 KB
    __shared__ float s_h[240 * HSTRIDE];            // 7440 floats = 29.8 KB

    const int b   = blockIdx.y;
    const int rg  = blockIdx.x;
    const int i0  = (rg < 2) ? rg * 8 : 16 + (rg - 2) * 7;
    const int nr  = (rg < 2) ? 8 : 7;
    const int tid = threadIdx.x;
    const int half = __builtin_amdgcn_readfirstlane(tid >> 8);  // wave-uniform
    const int cell = tid & 255;

    // --- stage state rows [i0, i0+nr+2) and the full image into LDS ---
    if (!FIRST) {
        const int n4 = (nr + 2) * NPIX * CSTATE / 4;   // divisible by 4
        const float4* gstate4 =
            (const float4*)(state_old + ((size_t)b * NPIX + i0) * NPIX * CSTATE);
        float4* s_state4 = (float4*)s_state;
        for (int t = tid; t < n4; t += 512) s_state4[t] = gstate4[t];
    }
    if (tid < NPIX * NPIX / 4) {
        ((float4*)s_img)[tid] = ((const float4*)(img + (size_t)b * NPIX * NPIX))[tid];
    }
    __syncthreads();

    const int cells = nr * NNEO;
    const bool active = cell < cells;

    int r = 0, j = 0, i = 0, gcell = 0, px = 0, py = 0;
    if (active) {
        r = cell / NNEO;
        j = cell % NNEO;
        i = i0 + r;
        gcell = (b * NNEO + i) * NNEO + j;
        if (FIRST) { px = i; py = j; }
        else       { px = perc[2 * gcell]; py = perc[2 * gcell + 1]; }
    }

    // ---------------- layer 1: 182 -> 30 (this thread: 15) ----------------
    float h1[15];
    {
        const float* __restrict__ bb = b1 + 15 * half;
#pragma unroll
        for (int q = 0; q < 15; q++) h1[q] = bb[q];
    }
    if (active) {
#pragma unroll
        for (int pr = 0; pr < 3; pr++) {
#pragma unroll
            for (int pc = 0; pc < 3; pc++) {
                const int p9 = pr * 3 + pc;
                const float iv = s_img[(px + pr) * NPIX + (py + pc)];
                {
                    const float* __restrict__ wr = W1 + (p9 * 20) * 30 + 15 * half;
#pragma unroll
                    for (int q = 0; q < 15; q++) h1[q] += iv * wr[q];
                }
                if (!FIRST) {
                    const int sbase = ((r + pr) * NPIX + (j + pc)) * CSTATE;
                    float fv[CSTATE];
#pragma unroll
                    for (int ch = 0; ch < CSTATE; ch++) fv[ch] = s_state[sbase + ch];
#pragma unroll
                    for (int ch = 0; ch < CSTATE; ch++) {
                        const float* __restrict__ wr =
                            W1 + (p9 * 20 + 1 + ch) * 30 + 15 * half;
#pragma unroll
                        for (int q = 0; q < 15; q++) h1[q] += fv[ch] * wr[q];
                    }
                }
            }
        }
        const float posx = (float)(px - 16) * (1.0f / 16.0f);
        const float posy = (float)(py - 16) * (1.0f / 16.0f);
        const float* __restrict__ wx = W1 + 180 * 30 + 15 * half;
        const float* __restrict__ wy = W1 + 181 * 30 + 15 * half;
#pragma unroll
        for (int q = 0; q < 15; q++) h1[q] += posx * wx[q];
#pragma unroll
        for (int q = 0; q < 15; q++) h1[q] += posy * wy[q];
#pragma unroll
        for (int q = 0; q < 15; q++) h1[q] = fmaxf(h1[q], 0.0f);
        // publish my half of h1
#pragma unroll
        for (int q = 0; q < 15; q++) s_h[cell * HSTRIDE + 15 * half + q] = h1[q];
    }
    __syncthreads();

    // ---------------- layer 2: 30 -> 30 (this thread: 15) ----------------
    float h2[15];
    {
        const float* __restrict__ bb = b2 + 15 * half;
#pragma unroll
        for (int q = 0; q < 15; q++) h2[q] = bb[q];
    }
    if (active) {
        float a1[30];
#pragma unroll
        for (int k = 0; k < 30; k++) a1[k] = s_h[cell * HSTRIDE + k];
#pragma unroll
        for (int k = 0; k < 30; k++) {
            const float* __restrict__ wr = W2 + k * 30 + 15 * half;
#pragma unroll
            for (int q = 0; q < 15; q++) h2[q] += a1[k] * wr[q];
        }
#pragma unroll
        for (int q = 0; q < 15; q++) h2[q] = fmaxf(h2[q], 0.0f);
    }
    __syncthreads();   // all a1 reads done before overwrite
    if (active) {
#pragma unroll
        for (int q = 0; q < 15; q++) s_h[cell * HSTRIDE + 15 * half + q] = h2[q];
    }
    __syncthreads();

    // ---------------- layer 3: 30 -> 21 (half0: c 0..10, half1: c 11..20) --
    const int c0   = half ? 11 : 0;
    const int nout = half ? 10 : 11;
    float o[11];
#pragma unroll
    for (int c = 0; c < 11; c++) o[c] = (c < nout) ? b3[c0 + c] : 0.0f;
    if (active) {
        float a2[30];
#pragma unroll
        for (int k = 0; k < 30; k++) a2[k] = s_h[cell * HSTRIDE + k];
        if (half) {
#pragma unroll
            for (int k = 0; k < 30; k++) {
                const float* __restrict__ wr = W3 + k * 21 + 11;
#pragma unroll
                for (int c = 0; c < 10; c++) o[c] += a2[k] * wr[c];
            }
        } else {
#pragma unroll
            for (int k = 0; k < 30; k++) {
                const float* __restrict__ wr = W3 + k * 21;
#pragma unroll
                for (int c = 0; c < 11; c++) o[c] += a2[k] * wr[c];
            }
        }

        const int lcenter = ((r + 1) * NPIX + (j + 1)) * CSTATE;
        if (!LAST) {
            float* __restrict__ ns =
                state_new + (((size_t)b * NPIX + (i + 1)) * NPIX + (j + 1)) * CSTATE;
            if (half == 0) {
#pragma unroll
                for (int c = 0; c < 11; c++)
                    ns[c] = (FIRST ? 0.0f : s_state[lcenter + c]) + o[c];
            } else {
#pragma unroll
                for (int c = 0; c < 8; c++)   // ch 11..18
                    ns[11 + c] = (FIRST ? 0.0f : s_state[lcenter + 11 + c]) + o[c];
                // movement: ch19 = o[8], ch20 = o[9]
                int dxm = (o[8] > THRESHV) ? 1 : ((o[8] < -THRESHV) ? -1 : 0);
                int dym = (o[9] > THRESHV) ? 1 : ((o[9] < -THRESHV) ? -1 : 0);
                px += dxm; py += dym;
                px = (px < 0) ? 0 : ((px > NNEO - 1) ? NNEO - 1 : px);
                py = (py < 0) ? 0 : ((py > NNEO - 1) ? NNEO - 1 : py);
                perc[2 * gcell + 0] = px;
                perc[2 * gcell + 1] = py;
            }
        } else {
            // final step: skip state/perc writes; emit guesses + class_state
            float* __restrict__ g = guesses_out + (size_t)gcell * OUTD;
            if (half == 0) {
#pragma unroll
                for (int c = 0; c < 11; c++) g[c] = o[c];
            } else {
#pragma unroll
                for (int c = 0; c < 10; c++) g[11 + c] = o[c];
                // class channels 16..18 = center state + o[5..7]  (11+5 = 16)
                float* __restrict__ cs = class_out + (size_t)gcell * 3;
#pragma unroll
                for (int cc = 0; cc < 3; cc++)
                    cs[cc] = s_state[lcenter + 16 + cc] + o[5 + cc];
            }
        }
    }
}

extern "C" void kernel_launch(void* const* d_in, const int* in_sizes, int n_in,
                              void* d_out, int out_size, void* d_ws, size_t ws_size,
                              hipStream_t stream) {
    const float* img = (const float*)d_in[0];
    const float* W1  = (const float*)d_in[1];
    const float* b1  = (const float*)d_in[2];
    const float* W2  = (const float*)d_in[3];
    const float* b2  = (const float*)d_in[4];
    const float* W3  = (const float*)d_in[5];
    const float* b3  = (const float*)d_in[6];

    float* out = (float*)d_out;
    float* class_out   = out;                 // 345,600 floats
    float* guesses_out = out + CLASS_ELEMS;   // 2,419,200 floats

    float* stateA = (float*)d_ws;
    float* stateB = stateA + STATE_ELEMS;
    int*   perc   = (int*)(stateB + STATE_ELEMS);

    {
        const int total = B_ * 124 * CSTATE;
        nca_init<<<(total + 255) / 256, 256, 0, stream>>>(stateA, stateB);
    }

    const dim3 grid(4, B_);
    for (int t = 0; t < ITERS; t++) {
        const float* so = (t & 1) ? stateB : stateA;
        float*       sn = (t & 1) ? stateA : stateB;
        if (t == 0) {
            nca_step<true, false><<<grid, 512, 0, stream>>>(
                img, W1, b1, W2, b2, W3, b3, so, sn, perc, guesses_out, class_out);
        } else if (t == ITERS - 1) {
            nca_step<false, true><<<grid, 512, 0, stream>>>(
                img, W1, b1, W2, b2, W3, b3, so, sn, perc, guesses_out, class_out);
        } else {
            nca_step<false, false><<<grid, 512, 0, stream>>>(
                img, W1, b1, W2, b2, W3, b3, so, sn, perc, guesses_out, class_out);
        }
    }
}

// Round 5
// 369.123 us; speedup vs baseline: 1.2077x; 1.2077x over previous
//
#include <hip/hip_runtime.h>

// Problem constants (from reference)
#define B_      128
#define NPIX    32      // N = M = 32
#define NNEO    30      // N-2
#define CSTATE  19      // state channels
#define OUTD    21      // OUT_DIM
#define ITERS   10
#define THRESHV 0.0007f

#define STATE_ELEMS (B_ * NPIX * NPIX * CSTATE)   // 2,490,368 floats per buffer
#define NCELLS      (B_ * NNEO * NNEO)            // 115,200
#define CLASS_ELEMS (NCELLS * 3)                  // 345,600
#define HSTRIDE 31    // s_h cell stride: gcd(31,32)=1 -> conflict-free

// ---------------------------------------------------------------------------
// init: zero ONLY the borders of both state buffers (interiors are fully
// written by each step before being read). perc needs no init: step t=0
// derives (px,py)=(i,j) itself.
// ---------------------------------------------------------------------------
__global__ void nca_init(float* __restrict__ stateA, float* __restrict__ stateB) {
    int idx = blockIdx.x * blockDim.x + threadIdx.x;
    const int total = B_ * 124 * CSTATE;
    if (idx >= total) return;
    int c  = idx % CSTATE;
    int t2 = idx / CSTATE;
    int cell = t2 % 124;
    int b    = t2 / 124;
    int i, j;
    if (cell < 32)      { i = 0;  j = cell; }
    else if (cell < 64) { i = 31; j = cell - 32; }
    else { int k = cell - 64; i = 1 + (k >> 1); j = (k & 1) ? 31 : 0; }
    size_t off = (((size_t)b * NPIX + i) * NPIX + j) * CSTATE + c;
    stateA[off] = 0.0f;
    stateB[off] = 0.0f;
}

// ---------------------------------------------------------------------------
// One NCA step. Block = (batch b, row-group rg): row groups {8,8,7,7}, 30
// cols, 1024 threads = 4 "quarters" of 4 waves. Quarter qh computes output
// slice [QOFF(qh), QOFF(qh)+8) of layers 1-2 (overlapping slices {0,8,14,22}
// keep widths uniform; duplicated outputs are bitwise identical) and slice
// [5*qh, 5*qh+6) of layer 3. 4 threads/cell -> 8 waves/SIMD for latency
// hiding; weight addresses wave-uniform (scalar loads). Loops left rolled:
// full unroll regressed (R4: compiler fell off the s_load path).
// ---------------------------------------------------------------------------
template<bool FIRST, bool LAST>
__global__ __launch_bounds__(1024, 8)
void nca_step(const float* __restrict__ img,
              const float* __restrict__ W1, const float* __restrict__ b1,
              const float* __restrict__ W2, const float* __restrict__ b2,
              const float* __restrict__ W3, const float* __restrict__ b3,
              const float* __restrict__ state_old, float* __restrict__ state_new,
              int* perc, float* __restrict__ guesses_out,
              float* __restrict__ class_out) {
    __shared__ float s_state[10 * NPIX * CSTATE];   // 6080 floats = 24.3 KB
    __shared__ float s_img[NPIX * NPIX];            // 1024 floats = 4 KB
    __shared__ float s_h[240 * HSTRIDE];            // 7440 floats = 29.8 KB

    const int b   = blockIdx.y;
    const int rg  = blockIdx.x;
    const int i0  = (rg < 2) ? rg * 8 : 16 + (rg - 2) * 7;
    const int nr  = (rg < 2) ? 8 : 7;
    const int tid = threadIdx.x;
    const int qh  = __builtin_amdgcn_readfirstlane(tid >> 8);   // wave-uniform
    const int cell = tid & 255;
    const int qoff = (qh == 0) ? 0 : (qh == 1) ? 8 : (qh == 2) ? 14 : 22;
    const int off3 = 5 * qh;

    // --- stage state rows [i0, i0+nr+2) and the full image into LDS ---
    if (!FIRST) {
        const int n4 = (nr + 2) * NPIX * CSTATE / 4;   // divisible by 4
        const float4* gstate4 =
            (const float4*)(state_old + ((size_t)b * NPIX + i0) * NPIX * CSTATE);
        float4* s_state4 = (float4*)s_state;
        for (int t = tid; t < n4; t += 1024) s_state4[t] = gstate4[t];
    }
    if (tid < NPIX * NPIX / 4) {
        ((float4*)s_img)[tid] = ((const float4*)(img + (size_t)b * NPIX * NPIX))[tid];
    }
    __syncthreads();

    const int cells = nr * NNEO;
    const bool active = cell < cells;

    int r = 0, j = 0, i = 0, gcell = 0, px = 0, py = 0;
    if (active) {
        r = cell / NNEO;
        j = cell % NNEO;
        i = i0 + r;
        gcell = (b * NNEO + i) * NNEO + j;
        if (FIRST) { px = i; py = j; }
        else       { px = perc[2 * gcell]; py = perc[2 * gcell + 1]; }
    }

    // ---------------- layer 1: 182 -> 30 (this thread: 8 @ qoff) ----------
    float h1[8];
    {
        const float* __restrict__ bb = b1 + qoff;
#pragma unroll
        for (int q = 0; q < 8; q++) h1[q] = bb[q];
    }
    if (active) {
        for (int pr = 0; pr < 3; pr++) {
            for (int pc = 0; pc < 3; pc++) {
                const int p9 = pr * 3 + pc;
                const float iv = s_img[(px + pr) * NPIX + (py + pc)];
                {
                    const float* __restrict__ wr = W1 + (p9 * 20) * 30 + qoff;
#pragma unroll
                    for (int q = 0; q < 8; q++) h1[q] += iv * wr[q];
                }
                if (!FIRST) {
                    const int sbase = ((r + pr) * NPIX + (j + pc)) * CSTATE;
                    float fv[CSTATE];
#pragma unroll
                    for (int ch = 0; ch < CSTATE; ch++) fv[ch] = s_state[sbase + ch];
                    for (int ch = 0; ch < CSTATE; ch++) {
                        const float* __restrict__ wr =
                            W1 + (p9 * 20 + 1 + ch) * 30 + qoff;
#pragma unroll
                        for (int q = 0; q < 8; q++) h1[q] += fv[ch] * wr[q];
                    }
                }
            }
        }
        const float posx = (float)(px - 16) * (1.0f / 16.0f);
        const float posy = (float)(py - 16) * (1.0f / 16.0f);
        const float* __restrict__ wx = W1 + 180 * 30 + qoff;
        const float* __restrict__ wy = W1 + 181 * 30 + qoff;
#pragma unroll
        for (int q = 0; q < 8; q++) h1[q] += posx * wx[q];
#pragma unroll
        for (int q = 0; q < 8; q++) h1[q] += posy * wy[q];
#pragma unroll
        for (int q = 0; q < 8; q++) h1[q] = fmaxf(h1[q], 0.0f);
        // publish my slice of h1 (overlapping slices write identical values)
#pragma unroll
        for (int q = 0; q < 8; q++) s_h[cell * HSTRIDE + qoff + q] = h1[q];
    }
    __syncthreads();

    // ---------------- layer 2: 30 -> 30 (this thread: 8 @ qoff) -----------
    float h2[8];
    {
        const float* __restrict__ bb = b2 + qoff;
#pragma unroll
        for (int q = 0; q < 8; q++) h2[q] = bb[q];
    }
    if (active) {
        float a1[30];
#pragma unroll
        for (int k = 0; k < 30; k++) a1[k] = s_h[cell * HSTRIDE + k];
        for (int k = 0; k < 30; k++) {
            const float* __restrict__ wr = W2 + k * 30 + qoff;
#pragma unroll
            for (int q = 0; q < 8; q++) h2[q] += a1[k] * wr[q];
        }
#pragma unroll
        for (int q = 0; q < 8; q++) h2[q] = fmaxf(h2[q], 0.0f);
    }
    __syncthreads();   // all a1 reads done before overwrite
    if (active) {
#pragma unroll
        for (int q = 0; q < 8; q++) s_h[cell * HSTRIDE + qoff + q] = h2[q];
    }
    __syncthreads();

    // ---------------- layer 3: 30 -> 21 (this thread: 6 @ off3) -----------
    float o[6];
    {
        const float* __restrict__ bb = b3 + off3;
#pragma unroll
        for (int c = 0; c < 6; c++) o[c] = bb[c];
    }
    if (active) {
        float a2[30];
#pragma unroll
        for (int k = 0; k < 30; k++) a2[k] = s_h[cell * HSTRIDE + k];
        for (int k = 0; k < 30; k++) {
            const float* __restrict__ wr = W3 + k * 21 + off3;
#pragma unroll
            for (int c = 0; c < 6; c++) o[c] += a2[k] * wr[c];
        }

        const int lcenter = ((r + 1) * NPIX + (j + 1)) * CSTATE;
        if (!LAST) {
            float* __restrict__ ns =
                state_new + (((size_t)b * NPIX + (i + 1)) * NPIX + (j + 1)) * CSTATE;
            // disjoint channel slices: q0 -> ch0-5, q1 -> ch6-10,
            // q2 -> ch11-15, q3 -> ch16-18 + movement (ch19,20 = o[4],o[5])
            if (qh == 0) {
#pragma unroll
                for (int c = 0; c < 6; c++)
                    ns[c] = (FIRST ? 0.0f : s_state[lcenter + c]) + o[c];
            } else if (qh < 3) {
#pragma unroll
                for (int c = 1; c < 6; c++)
                    ns[off3 + c] = (FIRST ? 0.0f : s_state[lcenter + off3 + c]) + o[c];
            } else {
#pragma unroll
                for (int c = 1; c < 4; c++)
                    ns[15 + c] = (FIRST ? 0.0f : s_state[lcenter + 15 + c]) + o[c];
                int dxm = (o[4] > THRESHV) ? 1 : ((o[4] < -THRESHV) ? -1 : 0);
                int dym = (o[5] > THRESHV) ? 1 : ((o[5] < -THRESHV) ? -1 : 0);
                px += dxm; py += dym;
                px = (px < 0) ? 0 : ((px > NNEO - 1) ? NNEO - 1 : px);
                py = (py < 0) ? 0 : ((py > NNEO - 1) ? NNEO - 1 : py);
                perc[2 * gcell + 0] = px;
                perc[2 * gcell + 1] = py;
            }
        } else {
            // final step: emit guesses + class_state only
            float* __restrict__ g = guesses_out + (size_t)gcell * OUTD;
            if (qh == 0) {
#pragma unroll
                for (int c = 0; c < 6; c++) g[c] = o[c];
            } else {
#pragma unroll
                for (int c = 1; c < 6; c++) g[off3 + c] = o[c];
            }
            if (qh == 3) {
                // class channels 16..18 = center state + o[1..3]
                float* __restrict__ cs = class_out + (size_t)gcell * 3;
#pragma unroll
                for (int cc = 0; cc < 3; cc++)
                    cs[cc] = s_state[lcenter + 16 + cc] + o[1 + cc];
            }
        }
    }
}

extern "C" void kernel_launch(void* const* d_in, const int* in_sizes, int n_in,
                              void* d_out, int out_size, void* d_ws, size_t ws_size,
                              hipStream_t stream) {
    const float* img = (const float*)d_in[0];
    const float* W1  = (const float*)d_in[1];
    const float* b1  = (const float*)d_in[2];
    const float* W2  = (const float*)d_in[3];
    const float* b2  = (const float*)d_in[4];
    const float* W3  = (const float*)d_in[5];
    const float* b3  = (const float*)d_in[6];

    float* out = (float*)d_out;
    float* class_out   = out;                 // 345,600 floats
    float* guesses_out = out + CLASS_ELEMS;   // 2,419,200 floats

    float* stateA = (float*)d_ws;
    float* stateB = stateA + STATE_ELEMS;
    int*   perc   = (int*)(stateB + STATE_ELEMS);

    {
        const int total = B_ * 124 * CSTATE;
        nca_init<<<(total + 255) / 256, 256, 0, stream>>>(stateA, stateB);
    }

    const dim3 grid(4, B_);
    for (int t = 0; t < ITERS; t++) {
        const float* so = (t & 1) ? stateB : stateA;
        float*       sn = (t & 1) ? stateA : stateB;
        if (t == 0) {
            nca_step<true, false><<<grid, 1024, 0, stream>>>(
                img, W1, b1, W2, b2, W3, b3, so, sn, perc, guesses_out, class_out);
        } else if (t == ITERS - 1) {
            nca_step<false, true><<<grid, 1024, 0, stream>>>(
                img, W1, b1, W2, b2, W3, b3, so, sn, perc, guesses_out, class_out);
        } else {
            nca_step<false, false><<<grid, 1024, 0, stream>>>(
                img, W1, b1, W2, b2, W3, b3, so, sn, perc, guesses_out, class_out);
        }
    }
}